// Round 1
// baseline (749.791 us; speedup 1.0000x reference)
//
#include <hip/hip_runtime.h>
#include <math.h>

#ifndef M_PI
#define M_PI 3.14159265358979323846
#endif

namespace {

constexpr int NF = 128;   // feature width
constexpr int NM = 25;    // total m components (l=0..4)

// ================= compile-time real Clebsch-Gordan tables =================
struct CD { double re, im; };
constexpr CD cmulc(CD x, CD y){ return CD{x.re*y.re - x.im*y.im, x.re*y.im + x.im*y.re}; }

constexpr double cfact(int n){ double r = 1.0; for (int i = 2; i <= n; ++i) r *= (double)i; return r; }

constexpr double csqrt_(double x){
  if (x <= 0.0) return 0.0;
  double g = x < 1.0 ? 1.0 : x;
  for (int i = 0; i < 48; ++i) g = 0.5 * (g + x / g);
  return g;
}

constexpr double cgc_(int l1, int l2, int l3, int m1, int m2, int m3){
  if (m1 + m2 != m3) return 0.0;
  int dmin = l1 > l2 ? l1 - l2 : l2 - l1;
  if (l3 < dmin || l3 > l1 + l2) return 0.0;
  double pre = csqrt_((2.0*l3 + 1.0) * cfact(l3 + l1 - l2) * cfact(l3 - l1 + l2) *
                      cfact(l1 + l2 - l3) / cfact(l1 + l2 + l3 + 1));
  pre *= csqrt_(cfact(l3 + m3) * cfact(l3 - m3) * cfact(l1 - m1) * cfact(l1 + m1) *
                cfact(l2 - m2) * cfact(l2 + m2));
  double s = 0.0;
  for (int k = 0; k <= l1 + l2 - l3; ++k){
    int a0 = k, a1 = l1 + l2 - l3 - k, a2 = l1 - m1 - k;
    int a3 = l2 + m2 - k, a4 = l3 - l2 + m1 + k, a5 = l3 - l1 - m2 + k;
    if (a0 < 0 || a1 < 0 || a2 < 0 || a3 < 0 || a4 < 0 || a5 < 0) continue;
    double d = cfact(a0)*cfact(a1)*cfact(a2)*cfact(a3)*cfact(a4)*cfact(a5);
    s += ((k & 1) ? -1.0 : 1.0) / d;
  }
  return pre * s;
}

constexpr CD umat(int l, int a, int A){
  const double is2 = 0.70710678118654752440;
  int ma = a - l, mA = A - l;
  if (ma == 0) return (mA == 0) ? CD{1.0, 0.0} : CD{0.0, 0.0};
  if (ma > 0){
    double sg = (ma & 1) ? -1.0 : 1.0;
    if (mA ==  ma) return CD{sg * is2, 0.0};
    if (mA == -ma) return CD{0.0, sg * is2};
    return CD{0.0, 0.0};
  }
  if (mA == -ma) return CD{is2, 0.0};
  if (mA ==  ma) return CD{0.0, -is2};
  return CD{0.0, 0.0};
}

struct TpEntry { int a, b, c, p; float v; };
struct TpTable { TpEntry e[1024]; int n; int npaths; };

constexpr TpTable build_tp(){
  TpTable T{};
  T.n = 0;
  int p = 0;
  for (int l1 = 0; l1 < 3; ++l1)
  for (int l2 = 0; l2 < 5; ++l2)
  for (int l3 = 0; l3 < 5; ++l3){
    int dmin = l1 > l2 ? l1 - l2 : l2 - l1;
    if (l3 < dmin || l3 > l1 + l2) continue;
    if ((l1 + l2 + l3) & 1) continue;
    double Cr[5][9][9] = {};
    for (int a = 0; a <= 2*l1; ++a)
    for (int b = 0; b <= 2*l2; ++b){
      int m1 = a - l1, m2 = b - l2, m3 = m1 + m2;
      if (m3 < -l3 || m3 > l3) continue;
      double cg = cgc_(l1, l2, l3, m1, m2, m3);
      if (cg == 0.0) continue;
      int c3 = l3 + m3;
      int Al[2] = { l1 + m1, l1 - m1 }; int nA = (m1 == 0) ? 1 : 2;
      int Bl[2] = { l2 + m2, l2 - m2 }; int nB = (m2 == 0) ? 1 : 2;
      int Cl[2] = { l3 + m3, l3 - m3 }; int nC = (m3 == 0) ? 1 : 2;
      for (int ia = 0; ia < nA; ++ia)
      for (int ib = 0; ib < nB; ++ib)
      for (int ic = 0; ic < nC; ++ic){
        CD u1 = umat(l1, a, Al[ia]);
        CD u2 = umat(l2, b, Bl[ib]);
        CD u3 = umat(l3, c3, Cl[ic]);
        CD t12 = cmulc(u1, u2);
        double re = t12.re * u3.re + t12.im * u3.im;   // Re(t12 * conj(u3))
        Cr[Al[ia]][Bl[ib]][Cl[ic]] += cg * re;
      }
    }
    for (int A = 0; A <= 2*l1; ++A)
    for (int B = 0; B <= 2*l2; ++B)
    for (int Cc = 0; Cc <= 2*l3; ++Cc){
      double v = Cr[A][B][Cc];
      if (v > 1e-12 || v < -1e-12){
        T.e[T.n].a = l1*l1 + A;
        T.e[T.n].b = l2*l2 + B;
        T.e[T.n].c = l3*l3 + Cc;
        T.e[T.n].p = p;
        T.e[T.n].v = (float)v;
        ++T.n;
      }
    }
    ++p;
  }
  T.npaths = p;
  return T;
}

constexpr TpTable TPT = build_tp();
constexpr int TPN      = TPT.n;
constexpr int NPATHS_C = TPT.npaths;
static_assert(NPATHS_C == 23, "path count mismatch vs reference PATHS");
static_assert(TPN <= 1024, "TP table overflow");

// Sorted copy: grouped by (c<13 ? 0 : 1) major, then by b ascending (enables
// register-caching of y2[b] in the unrolled TP loop, and wave-uniform halves).
struct TpSorted { TpEntry e[1024]; int n; int split; };
constexpr TpSorted sort_tp(){
  TpSorted S{}; S.n = TPT.n; S.split = 0;
  int k = 0;
  for (int half = 0; half < 2; ++half){
    for (int b = 0; b < NM; ++b)
      for (int t = 0; t < TPT.n; ++t){
        int h = (TPT.e[t].c >= 13) ? 1 : 0;
        if (h == half && TPT.e[t].b == b) S.e[k++] = TPT.e[t];
      }
    if (half == 0) S.split = k;
  }
  return S;
}
constexpr TpSorted STP = sort_tp();
static_assert(STP.n == TPN, "sort lost entries");
constexpr int TP_SPLIT = STP.split;

// ================= MFMA helpers =================
using bfrag = __attribute__((ext_vector_type(8))) short;   // 8 bf16
using f32x4 = __attribute__((ext_vector_type(4))) float;

__device__ __forceinline__ unsigned short bf16rn(float x){
  unsigned u = __float_as_uint(x);
  unsigned r = (u + 0x7FFFu + ((u >> 16) & 1u)) >> 16;
  return (unsigned short)r;
}
__device__ __forceinline__ float bfhi_to_f(unsigned short h){
  return __uint_as_float((unsigned)h << 16);
}

constexpr int T_STRIDE = 136;  // bf16 elements per padded t-row (breaks A-frag bank conflicts)
constexpr int Y_STRIDE = 129;  // fp32 elements per padded y2 row

// ================= prep kernel: swizzle W1/W2 into B-fragment order, bf16 hi/lo ==========
// B-frag for mfma_f32_16x16x32_bf16: lane L holds B[k = 8*(L>>4)+j][n = L&15], j=0..7.
// Frag id = (l*8 + nt)*4 + ks ; element offset = frag*512 + L*8 + j (shorts).
__global__ __launch_bounds__(256) void prep_kernel(const float* __restrict__ W1,
                                                   const float* __restrict__ W2,
                                                   short* __restrict__ W1hi, short* __restrict__ W1lo,
                                                   short* __restrict__ W2hi, short* __restrict__ W2lo){
  const int t = blockIdx.x * 256 + threadIdx.x;      // 0 .. 20479
  const int arr  = t / 10240;                        // 0: W1, 1: W2
  const int s    = t % 10240;
  const int lane = s & 63;
  const int ks   = (s >> 6) & 3;
  const int nt   = (s >> 8) & 7;
  const int l    = s >> 11;                          // 0..4
  const float* W = arr ? W2 : W1;
  short* Hi = arr ? W2hi : W1hi;
  short* Lo = arr ? W2lo : W1lo;
  const int g = 16 * nt + (lane & 15);
  short hi8[8], lo8[8];
  #pragma unroll
  for (int j = 0; j < 8; ++j){
    const int f = 32 * ks + 8 * (lane >> 4) + j;
    const float w = W[(l * NF + f) * NF + g];
    unsigned short h = bf16rn(w);
    hi8[j] = (short)h;
    lo8[j] = (short)bf16rn(w - bfhi_to_f(h));
  }
  const size_t off = (size_t)s * 8;
  *(bfrag*)(Hi + off) = *(bfrag*)hi8;
  *(bfrag*)(Lo + off) = *(bfrag*)lo8;
}

// ================= shared GEMM body =================
// Computes acc[l][n2] (16x16 C-tiles) = t(hi+lo) @ W(hi+lo), per-l padded tiles.
// tHi/tLo: LDS, padded rows (32 x T_STRIDE). Whi/Wlo: swizzled global.
__device__ __forceinline__ void mfma_gemm(const unsigned short* tHi, const unsigned short* tLo,
                                          const short* __restrict__ Whi, const short* __restrict__ Wlo,
                                          int lane, int wave, f32x4 acc[5][2]){
  const int quad = lane >> 4, l16 = lane & 15;
  #pragma unroll
  for (int l = 0; l < 5; ++l){
    const int mb = l * l;
    #pragma unroll
    for (int ks = 0; ks < 4; ++ks){
      const bfrag ah = *(const bfrag*)&tHi[(mb + l16) * T_STRIDE + 32 * ks + 8 * quad];
      const bfrag al = *(const bfrag*)&tLo[(mb + l16) * T_STRIDE + 32 * ks + 8 * quad];
      #pragma unroll
      for (int n2 = 0; n2 < 2; ++n2){
        const int nt = 2 * wave + n2;
        const size_t off = ((size_t)((l * 8 + nt) * 4 + ks)) * 512 + lane * 8;
        const bfrag bh = *(const bfrag*)(Whi + off);
        const bfrag bl = *(const bfrag*)(Wlo + off);
        acc[l][n2] = __builtin_amdgcn_mfma_f32_16x16x32_bf16(ah, bh, acc[l][n2], 0, 0, 0);
        acc[l][n2] = __builtin_amdgcn_mfma_f32_16x16x32_bf16(al, bh, acc[l][n2], 0, 0, 0);
        acc[l][n2] = __builtin_amdgcn_mfma_f32_16x16x32_bf16(ah, bl, acc[l][n2], 0, 0, 0);
      }
    }
  }
}

// ================= kernel A: per-atom Z = W1 @ A (no bias) =================
__global__ __launch_bounds__(256, 4) void atoms_kernel(const float* __restrict__ A,
                                                       const short* __restrict__ W1hi,
                                                       const short* __restrict__ W1lo,
                                                       float* __restrict__ Z){
  __shared__ unsigned short aHi[32 * T_STRIDE];
  __shared__ unsigned short aLo[32 * T_STRIDE];
  const int n   = blockIdx.x;
  const int tid = threadIdx.x;
  const int f   = tid & 127, half = tid >> 7;
  const float* Ab = A + (size_t)n * NM * NF;

  const int m0 = half ? 13 : 0, m1 = half ? 25 : 13;
  for (int m = m0; m < m1; ++m){
    const float x = Ab[m * NF + f];
    const unsigned short h = bf16rn(x);
    aHi[m * T_STRIDE + f] = h;
    aLo[m * T_STRIDE + f] = bf16rn(x - bfhi_to_f(h));
  }
  if (half){
    for (int m = 25; m < 32; ++m){ aHi[m * T_STRIDE + f] = 0; aLo[m * T_STRIDE + f] = 0; }
  }
  __syncthreads();

  const int lane = tid & 63, wave = tid >> 6;
  f32x4 acc[5][2];
  #pragma unroll
  for (int l = 0; l < 5; ++l)
    #pragma unroll
    for (int n2 = 0; n2 < 2; ++n2)
      acc[l][n2] = f32x4{0.f, 0.f, 0.f, 0.f};

  mfma_gemm(aHi, aLo, W1hi, W1lo, lane, wave, acc);

  const int quad = lane >> 4, l16 = lane & 15;
  float* Zb = Z + (size_t)n * NM * NF;
  #pragma unroll
  for (int l = 0; l < 5; ++l)
    #pragma unroll
    for (int n2 = 0; n2 < 2; ++n2){
      const int col = 16 * (2 * wave + n2) + l16;
      #pragma unroll
      for (int r = 0; r < 4; ++r){
        if (r <= 2 * l){                       // compile-time prune
          const int row = 4 * quad + r;
          if (row <= 2 * l)                    // runtime lane mask
            Zb[(l * l + row) * NF + col] = acc[l][n2][r];
        }
      }
    }
}

// ================= TP accumulation (compile-time partitioned) =================
template<int CG>
__device__ __forceinline__ void tp_accum(const float* y2col /* = &y2_lds[g] */,
                                         const float bd[9], const float wp[NPATHS_C],
                                         float o[13]){
  constexpr int t0 = (CG == 0) ? 0 : TP_SPLIT;
  constexpr int t1 = (CG == 0) ? TP_SPLIT : TPN;
  constexpr int cbase = (CG == 0) ? 0 : 13;
  float y2b = 0.f;
  #pragma unroll
  for (int t = t0; t < t1; ++t){
    if (t == t0 || STP.e[t].b != STP.e[t-1].b)     // folds at compile time
      y2b = y2col[STP.e[t].b * Y_STRIDE];
    o[STP.e[t].c - cbase] = fmaf(STP.e[t].v * wp[STP.e[t].p],
                                 bd[STP.e[t].a] * y2b,
                                 o[STP.e[t].c - cbase]);
  }
}

// ================= kernel B: per-edge fused pipeline =================
__global__ __launch_bounds__(256, 4) void edge_kernel(const float* __restrict__ Z,
                                                      const int*   __restrict__ nbr,
                                                      const float* __restrict__ disp,
                                                      const float* __restrict__ b1,
                                                      const short* __restrict__ W2hi,
                                                      const short* __restrict__ W2lo,
                                                      const float* __restrict__ b2,
                                                      const float* __restrict__ W3,
                                                      const float* __restrict__ b3,
                                                      const float* __restrict__ wtp,
                                                      float* __restrict__ out){
  __shared__ unsigned short tHi[32 * T_STRIDE];
  __shared__ unsigned short tLo[32 * T_STRIDE];
  __shared__ float y2_lds[NM * Y_STRIDE];
  __shared__ float rad_s[NF];
  __shared__ float rw_lds[3 * NF];
  __shared__ float nbuf[2 * NF];
  __shared__ float y0buf[NF];

  const int e   = blockIdx.x;
  const int tid = threadIdx.x;
  const int f   = tid & 127, half = tid >> 7;
  const int i = nbr[2 * e], j = nbr[2 * e + 1];
  const float* Zi = Z + (size_t)i * NM * NF;
  const float* Zj = Z + (size_t)j * NM * NF;

  // ---- P1a: partial norm + radial basis ----
  const int m0 = half ? 13 : 0, m1 = half ? 25 : 13;
  float n2 = 0.f;
  for (int m = m0; m < m1; ++m){
    float v = Zi[m * NF + f] + Zj[m * NF + f];
    if (m == 0) v += b1[f];
    n2 = fmaf(v, v, n2);
    if (m == 0) y0buf[f] = v;
  }
  nbuf[half * NF + f] = n2;

  const float dx = disp[3 * e], dy = disp[3 * e + 1], dz = disp[3 * e + 2];
  const float r  = sqrtf(dx * dx + dy * dy + dz * dz + 1e-12f);
  if (!half){
    const float uc = r * 0.2f;
    const float den = fmaxf(1.f - uc * uc, 1e-9f);
    const float cut = (uc < 1.f) ? expf(1.f - 1.f / den) : 0.f;
    rad_s[f] = cosf((float)f * ((float)M_PI * 0.2f) * r) * cut;
  }
  __syncthreads();

  // ---- P1b: normalize + gated mish -> t (bf16 hi/lo) in LDS ----
  const float inv = 1.0f / sqrtf(nbuf[f] + nbuf[NF + f] + 1e-6f);
  const float s   = y0buf[f] * inv;
  const float sp  = fmaxf(s, 0.f) + log1pf(expf(-fabsf(s)));
  const float th  = tanhf(sp);
  const float sg  = 1.0f / (1.0f + expf(-s));
  const float dm  = th + s * (1.f - th * th) * sg;
  for (int m = m0; m < m1; ++m){
    float v = Zi[m * NF + f] + Zj[m * NF + f];     // L1-hot reload
    if (m == 0) v += b1[f];
    const float tv = (m == 0) ? (s * th) : (v * inv * dm);
    const unsigned short h = bf16rn(tv);
    tHi[m * T_STRIDE + f] = h;
    tLo[m * T_STRIDE + f] = bf16rn(tv - bfhi_to_f(h));
  }
  if (half){
    for (int m = 25; m < 32; ++m){ tHi[m * T_STRIDE + f] = 0; tLo[m * T_STRIDE + f] = 0; }
  }
  __syncthreads();

  // ---- P2: W2 GEMM (split-bf16 MFMA) ----
  const int lane = tid & 63, wave = tid >> 6;
  f32x4 acc[5][2];
  #pragma unroll
  for (int l = 0; l < 5; ++l)
    #pragma unroll
    for (int c = 0; c < 2; ++c)
      acc[l][c] = f32x4{0.f, 0.f, 0.f, 0.f};

  mfma_gemm(tHi, tLo, W2hi, W2lo, lane, wave, acc);

  const int quad = lane >> 4, l16 = lane & 15;
  #pragma unroll
  for (int l = 0; l < 5; ++l)
    #pragma unroll
    for (int c = 0; c < 2; ++c){
      const int col = 16 * (2 * wave + c) + l16;
      #pragma unroll
      for (int rr = 0; rr < 4; ++rr){
        if (rr <= 2 * l){
          const int row = 4 * quad + rr;
          if (row <= 2 * l)
            y2_lds[(l * l + row) * Y_STRIDE + col] = acc[l][c][rr];
        }
      }
    }
  __syncthreads();

  // ---- P3: residual (+b2) and radial @ W3 ----
  for (int m = m0; m < m1; ++m){
    const float t_re = bfhi_to_f(tHi[m * T_STRIDE + f]) + bfhi_to_f(tLo[m * T_STRIDE + f]);
    float v = y2_lds[m * Y_STRIDE + f] + t_re;
    if (m == 0) v += b2[f];
    y2_lds[m * Y_STRIDE + f] = v;
  }
  if (!half){
    float a0 = 0.f;
    for (int q = 0; q < NF; ++q) a0 = fmaf(rad_s[q], W3[(0 * NF + q) * NF + f], a0);
    rw_lds[f] = a0;
  } else {
    float a1 = 0.f, a2 = 0.f;
    for (int q = 0; q < NF; ++q){
      const float rq = rad_s[q];
      a1 = fmaf(rq, W3[(1 * NF + q) * NF + f], a1);
      a2 = fmaf(rq, W3[(2 * NF + q) * NF + f], a2);
    }
    rw_lds[NF + f] = a1;
    rw_lds[2 * NF + f] = a2;
  }
  __syncthreads();

  // ---- P4: tensor product + store ----
  const float ux = dx / r, uy = dy / r, uz = dz / r;
  const float s3 = 1.7320508075688772f;
  float bd[9];
  {
    const float rw0 = rw_lds[f], rw1 = rw_lds[NF + f], rw2 = rw_lds[2 * NF + f];
    bd[0] = rw0 + b3[f];
    bd[1] = uy * rw1;
    bd[2] = uz * rw1;
    bd[3] = ux * rw1;
    bd[4] = (s3 * ux * uy) * rw2;
    bd[5] = (s3 * uy * uz) * rw2;
    bd[6] = (0.5f * (3.f * uz * uz - 1.f)) * rw2;
    bd[7] = (s3 * ux * uz) * rw2;
    bd[8] = (0.5f * s3 * (ux * ux - uy * uy)) * rw2;
  }
  float wp[NPATHS_C];
  #pragma unroll
  for (int p = 0; p < NPATHS_C; ++p) wp[p] = wtp[p * NF + f];

  float o[13];
  #pragma unroll
  for (int k = 0; k < 13; ++k) o[k] = 0.f;

  float* ob = out + (size_t)e * NM * NF;
  if (!half){
    tp_accum<0>(&y2_lds[f], bd, wp, o);
    #pragma unroll
    for (int k = 0; k < 13; ++k) ob[k * NF + f] = o[k];
  } else {
    tp_accum<1>(&y2_lds[f], bd, wp, o);
    #pragma unroll
    for (int k = 0; k < 12; ++k) ob[(13 + k) * NF + f] = o[k];
  }
}

} // anonymous namespace

extern "C" void kernel_launch(void* const* d_in, const int* in_sizes, int n_in,
                              void* d_out, int out_size, void* d_ws, size_t ws_size,
                              hipStream_t stream) {
  (void)n_in; (void)out_size;
  const float* A    = (const float*)d_in[0];
  const int*   nbr  = (const int*)  d_in[1];
  const float* disp = (const float*)d_in[2];
  const float* W1   = (const float*)d_in[3];
  const float* b1   = (const float*)d_in[4];
  const float* W2   = (const float*)d_in[5];
  const float* b2   = (const float*)d_in[6];
  const float* W3   = (const float*)d_in[7];
  const float* b3   = (const float*)d_in[8];
  const float* wtp  = (const float*)d_in[9];
  float* out = (float*)d_out;

  const int n_atoms = in_sizes[0] / (NM * NF);
  const int n_edges = in_sizes[1] / 2;

  // ws layout: 4 swizzled weight arrays (163840 B each) + Z (n_atoms*25*128 fp32)
  const size_t wsz   = (size_t)5 * 8 * 4 * 64 * 8 * sizeof(short);  // 163840 B
  const size_t zoff  = 4 * wsz;
  const size_t need  = zoff + (size_t)n_atoms * NM * NF * sizeof(float);
  if (ws_size < need) return;

  short* W1hi = (short*)((char*)d_ws + 0 * wsz);
  short* W1lo = (short*)((char*)d_ws + 1 * wsz);
  short* W2hi = (short*)((char*)d_ws + 2 * wsz);
  short* W2lo = (short*)((char*)d_ws + 3 * wsz);
  float* Z    = (float*)((char*)d_ws + zoff);

  prep_kernel<<<dim3(80), dim3(256), 0, stream>>>(W1, W2, W1hi, W1lo, W2hi, W2lo);
  atoms_kernel<<<dim3(n_atoms), dim3(256), 0, stream>>>(A, W1hi, W1lo, Z);
  edge_kernel<<<dim3(n_edges), dim3(256), 0, stream>>>(Z, nbr, disp, b1, W2hi, W2lo,
                                                       b2, W3, b3, wtp, out);
}

// Round 2
// 585.626 us; speedup vs baseline: 1.2803x; 1.2803x over previous
//
#include <hip/hip_runtime.h>
#include <math.h>

#ifndef M_PI
#define M_PI 3.14159265358979323846
#endif

namespace {

constexpr int NF = 128;   // feature width
constexpr int NM = 25;    // total m components (l=0..4)

// ================= compile-time real Clebsch-Gordan tables =================
struct CD { double re, im; };
constexpr CD cmulc(CD x, CD y){ return CD{x.re*y.re - x.im*y.im, x.re*y.im + x.im*y.re}; }

constexpr double cfact(int n){ double r = 1.0; for (int i = 2; i <= n; ++i) r *= (double)i; return r; }

constexpr double csqrt_(double x){
  if (x <= 0.0) return 0.0;
  double g = x < 1.0 ? 1.0 : x;
  for (int i = 0; i < 48; ++i) g = 0.5 * (g + x / g);
  return g;
}

constexpr double cgc_(int l1, int l2, int l3, int m1, int m2, int m3){
  if (m1 + m2 != m3) return 0.0;
  int dmin = l1 > l2 ? l1 - l2 : l2 - l1;
  if (l3 < dmin || l3 > l1 + l2) return 0.0;
  double pre = csqrt_((2.0*l3 + 1.0) * cfact(l3 + l1 - l2) * cfact(l3 - l1 + l2) *
                      cfact(l1 + l2 - l3) / cfact(l1 + l2 + l3 + 1));
  pre *= csqrt_(cfact(l3 + m3) * cfact(l3 - m3) * cfact(l1 - m1) * cfact(l1 + m1) *
                cfact(l2 - m2) * cfact(l2 + m2));
  double s = 0.0;
  for (int k = 0; k <= l1 + l2 - l3; ++k){
    int a0 = k, a1 = l1 + l2 - l3 - k, a2 = l1 - m1 - k;
    int a3 = l2 + m2 - k, a4 = l3 - l2 + m1 + k, a5 = l3 - l1 - m2 + k;
    if (a0 < 0 || a1 < 0 || a2 < 0 || a3 < 0 || a4 < 0 || a5 < 0) continue;
    double d = cfact(a0)*cfact(a1)*cfact(a2)*cfact(a3)*cfact(a4)*cfact(a5);
    s += ((k & 1) ? -1.0 : 1.0) / d;
  }
  return pre * s;
}

constexpr CD umat(int l, int a, int A){
  const double is2 = 0.70710678118654752440;
  int ma = a - l, mA = A - l;
  if (ma == 0) return (mA == 0) ? CD{1.0, 0.0} : CD{0.0, 0.0};
  if (ma > 0){
    double sg = (ma & 1) ? -1.0 : 1.0;
    if (mA ==  ma) return CD{sg * is2, 0.0};
    if (mA == -ma) return CD{0.0, sg * is2};
    return CD{0.0, 0.0};
  }
  if (mA == -ma) return CD{is2, 0.0};
  if (mA ==  ma) return CD{0.0, -is2};
  return CD{0.0, 0.0};
}

struct TpEntry { int a, b, c, p; float v; };
struct TpTable { TpEntry e[1024]; int n; int npaths; };

constexpr TpTable build_tp(){
  TpTable T{};
  T.n = 0;
  int p = 0;
  for (int l1 = 0; l1 < 3; ++l1)
  for (int l2 = 0; l2 < 5; ++l2)
  for (int l3 = 0; l3 < 5; ++l3){
    int dmin = l1 > l2 ? l1 - l2 : l2 - l1;
    if (l3 < dmin || l3 > l1 + l2) continue;
    if ((l1 + l2 + l3) & 1) continue;
    double Cr[5][9][9] = {};
    for (int a = 0; a <= 2*l1; ++a)
    for (int b = 0; b <= 2*l2; ++b){
      int m1 = a - l1, m2 = b - l2, m3 = m1 + m2;
      if (m3 < -l3 || m3 > l3) continue;
      double cg = cgc_(l1, l2, l3, m1, m2, m3);
      if (cg == 0.0) continue;
      int c3 = l3 + m3;
      int Al[2] = { l1 + m1, l1 - m1 }; int nA = (m1 == 0) ? 1 : 2;
      int Bl[2] = { l2 + m2, l2 - m2 }; int nB = (m2 == 0) ? 1 : 2;
      int Cl[2] = { l3 + m3, l3 - m3 }; int nC = (m3 == 0) ? 1 : 2;
      for (int ia = 0; ia < nA; ++ia)
      for (int ib = 0; ib < nB; ++ib)
      for (int ic = 0; ic < nC; ++ic){
        CD u1 = umat(l1, a, Al[ia]);
        CD u2 = umat(l2, b, Bl[ib]);
        CD u3 = umat(l3, c3, Cl[ic]);
        CD t12 = cmulc(u1, u2);
        double re = t12.re * u3.re + t12.im * u3.im;   // Re(t12 * conj(u3))
        Cr[Al[ia]][Bl[ib]][Cl[ic]] += cg * re;
      }
    }
    for (int A = 0; A <= 2*l1; ++A)
    for (int B = 0; B <= 2*l2; ++B)
    for (int Cc = 0; Cc <= 2*l3; ++Cc){
      double v = Cr[A][B][Cc];
      if (v > 1e-12 || v < -1e-12){
        T.e[T.n].a = l1*l1 + A;
        T.e[T.n].b = l2*l2 + B;
        T.e[T.n].c = l3*l3 + Cc;
        T.e[T.n].p = p;
        T.e[T.n].v = (float)v;
        ++T.n;
      }
    }
    ++p;
  }
  T.npaths = p;
  return T;
}

constexpr TpTable TPT = build_tp();
constexpr int TPN      = TPT.n;
constexpr int NPATHS_C = TPT.npaths;
static_assert(NPATHS_C == 23, "path count mismatch vs reference PATHS");
static_assert(TPN <= 1024, "TP table overflow");

// Sorted copy: grouped by (c<13 ? 0 : 1) major, then by b ascending (enables
// register-caching of y2[b] in the unrolled TP loop, and wave-uniform halves).
struct TpSorted { TpEntry e[1024]; int n; int split; };
constexpr TpSorted sort_tp(){
  TpSorted S{}; S.n = TPT.n; S.split = 0;
  int k = 0;
  for (int half = 0; half < 2; ++half){
    for (int b = 0; b < NM; ++b)
      for (int t = 0; t < TPT.n; ++t){
        int h = (TPT.e[t].c >= 13) ? 1 : 0;
        if (h == half && TPT.e[t].b == b) S.e[k++] = TPT.e[t];
      }
    if (half == 0) S.split = k;
  }
  return S;
}
constexpr TpSorted STP = sort_tp();
static_assert(STP.n == TPN, "sort lost entries");
constexpr int TP_SPLIT = STP.split;

// ================= MFMA helpers =================
using bfrag = __attribute__((ext_vector_type(8))) short;   // 8 bf16
using f32x4 = __attribute__((ext_vector_type(4))) float;

__device__ __forceinline__ unsigned short bf16rn(float x){
  unsigned u = __float_as_uint(x);
  unsigned r = (u + 0x7FFFu + ((u >> 16) & 1u)) >> 16;
  return (unsigned short)r;
}
__device__ __forceinline__ float bfhi_to_f(unsigned short h){
  return __uint_as_float((unsigned)h << 16);
}

constexpr int T_STRIDE = 136;  // bf16 elements per padded t-row (breaks A-frag bank conflicts)
constexpr int Y_STRIDE = 129;  // fp32 elements per padded y2 row

// ================= prep kernel: swizzle W1/W2/W3 into B-fragment order, bf16 hi/lo ==========
// B-frag for mfma_f32_16x16x32_bf16: lane L holds B[k = 8*(L>>4)+j][n = L&15], j=0..7.
// Frag id = (l*8 + nt)*4 + ks ; element offset = frag*512 + L*8 + j (shorts).
// W1/W2: l=0..4 (10240 frags-of-8 each). W3: l=0..2 (6144).
__global__ __launch_bounds__(256) void prep_kernel(const float* __restrict__ W1,
                                                   const float* __restrict__ W2,
                                                   const float* __restrict__ W3,
                                                   short* __restrict__ W1hi, short* __restrict__ W1lo,
                                                   short* __restrict__ W2hi, short* __restrict__ W2lo,
                                                   short* __restrict__ W3hi, short* __restrict__ W3lo){
  const int t = blockIdx.x * 256 + threadIdx.x;      // 0 .. 26623
  if (t >= 26624) return;
  int arr, s;
  if (t < 10240)      { arr = 0; s = t; }
  else if (t < 20480) { arr = 1; s = t - 10240; }
  else                { arr = 2; s = t - 20480; }
  const int lane = s & 63;
  const int ks   = (s >> 6) & 3;
  const int nt   = (s >> 8) & 7;
  const int l    = s >> 11;                          // 0..4 (0..2 for W3)
  const float* W = (arr == 0) ? W1 : (arr == 1) ? W2 : W3;
  short* Hi = (arr == 0) ? W1hi : (arr == 1) ? W2hi : W3hi;
  short* Lo = (arr == 0) ? W1lo : (arr == 1) ? W2lo : W3lo;
  const int g = 16 * nt + (lane & 15);
  short hi8[8], lo8[8];
  #pragma unroll
  for (int j = 0; j < 8; ++j){
    const int f = 32 * ks + 8 * (lane >> 4) + j;
    const float w = W[(l * NF + f) * NF + g];
    unsigned short h = bf16rn(w);
    hi8[j] = (short)h;
    lo8[j] = (short)bf16rn(w - bfhi_to_f(h));
  }
  const size_t off = (size_t)s * 8;
  *(bfrag*)(Hi + off) = *(bfrag*)hi8;
  *(bfrag*)(Lo + off) = *(bfrag*)lo8;
}

// ================= shared GEMM body =================
// Computes acc[l][n2] (16x16 C-tiles) = t(hi+lo) @ W(hi+lo), per-l padded tiles.
// tHi/tLo: LDS, padded rows (32 x T_STRIDE). Whi/Wlo: swizzled global.
__device__ __forceinline__ void mfma_gemm(const unsigned short* tHi, const unsigned short* tLo,
                                          const short* __restrict__ Whi, const short* __restrict__ Wlo,
                                          int lane, int wave, f32x4 acc[5][2]){
  const int quad = lane >> 4, l16 = lane & 15;
  #pragma unroll
  for (int l = 0; l < 5; ++l){
    const int mb = l * l;
    #pragma unroll
    for (int ks = 0; ks < 4; ++ks){
      const bfrag ah = *(const bfrag*)&tHi[(mb + l16) * T_STRIDE + 32 * ks + 8 * quad];
      const bfrag al = *(const bfrag*)&tLo[(mb + l16) * T_STRIDE + 32 * ks + 8 * quad];
      #pragma unroll
      for (int n2 = 0; n2 < 2; ++n2){
        const int nt = 2 * wave + n2;
        const size_t off = ((size_t)((l * 8 + nt) * 4 + ks)) * 512 + lane * 8;
        const bfrag bh = *(const bfrag*)(Whi + off);
        const bfrag bl = *(const bfrag*)(Wlo + off);
        acc[l][n2] = __builtin_amdgcn_mfma_f32_16x16x32_bf16(ah, bh, acc[l][n2], 0, 0, 0);
        acc[l][n2] = __builtin_amdgcn_mfma_f32_16x16x32_bf16(al, bh, acc[l][n2], 0, 0, 0);
        acc[l][n2] = __builtin_amdgcn_mfma_f32_16x16x32_bf16(ah, bl, acc[l][n2], 0, 0, 0);
      }
    }
  }
}

// ================= kernel A: per-atom Z = W1 @ A (no bias) =================
__global__ __launch_bounds__(256, 4) void atoms_kernel(const float* __restrict__ A,
                                                       const short* __restrict__ W1hi,
                                                       const short* __restrict__ W1lo,
                                                       float* __restrict__ Z){
  __shared__ unsigned short aHi[32 * T_STRIDE];
  __shared__ unsigned short aLo[32 * T_STRIDE];
  const int n   = blockIdx.x;
  const int tid = threadIdx.x;
  const int f   = tid & 127, half = tid >> 7;
  const float* Ab = A + (size_t)n * NM * NF;

  const int m0 = half ? 13 : 0, m1 = half ? 25 : 13;
  for (int m = m0; m < m1; ++m){
    const float x = Ab[m * NF + f];
    const unsigned short h = bf16rn(x);
    aHi[m * T_STRIDE + f] = h;
    aLo[m * T_STRIDE + f] = bf16rn(x - bfhi_to_f(h));
  }
  if (half){
    for (int m = 25; m < 32; ++m){ aHi[m * T_STRIDE + f] = 0; aLo[m * T_STRIDE + f] = 0; }
  }
  __syncthreads();

  const int lane = tid & 63, wave = tid >> 6;
  f32x4 acc[5][2];
  #pragma unroll
  for (int l = 0; l < 5; ++l)
    #pragma unroll
    for (int n2 = 0; n2 < 2; ++n2)
      acc[l][n2] = f32x4{0.f, 0.f, 0.f, 0.f};

  mfma_gemm(aHi, aLo, W1hi, W1lo, lane, wave, acc);

  const int quad = lane >> 4, l16 = lane & 15;
  float* Zb = Z + (size_t)n * NM * NF;
  #pragma unroll
  for (int l = 0; l < 5; ++l)
    #pragma unroll
    for (int n2 = 0; n2 < 2; ++n2){
      const int col = 16 * (2 * wave + n2) + l16;
      #pragma unroll
      for (int r = 0; r < 4; ++r){
        if (r <= 2 * l){                       // compile-time prune
          const int row = 4 * quad + r;
          if (row <= 2 * l)                    // runtime lane mask
            Zb[(l * l + row) * NF + col] = acc[l][n2][r];
        }
      }
    }
}

// ================= kernel R: batched radial GEMM rw = rad @ W3 (+b3 on l=0) ======
// 32 edges per block. Output parked in out[e] rows 0..2 (overwritten later by
// edge_kernel P4 AFTER it reads them — same-thread RAW, race-free).
__global__ __launch_bounds__(256) void radial_kernel(const float* __restrict__ disp,
                                                     const short* __restrict__ W3hi,
                                                     const short* __restrict__ W3lo,
                                                     const float* __restrict__ b3,
                                                     float* __restrict__ out,
                                                     int n_edges){
  __shared__ unsigned short rHi[32 * T_STRIDE];
  __shared__ unsigned short rLo[32 * T_STRIDE];
  __shared__ float rbuf[32];
  __shared__ float cbuf[32];
  const int e0  = blockIdx.x * 32;
  const int tid = threadIdx.x;
  if (tid < 32){
    const int e = e0 + tid;
    float r = 1.f, cut = 0.f;
    if (e < n_edges){
      const float dx = disp[3 * e], dy = disp[3 * e + 1], dz = disp[3 * e + 2];
      r = sqrtf(dx * dx + dy * dy + dz * dz + 1e-12f);
      const float uc  = r * 0.2f;
      const float den = fmaxf(1.f - uc * uc, 1e-9f);
      cut = (uc < 1.f) ? expf(1.f - 1.f / den) : 0.f;
    }
    rbuf[tid] = r; cbuf[tid] = cut;
  }
  __syncthreads();

  const int f = tid & 127, half = tid >> 7;
  #pragma unroll
  for (int mr = 0; mr < 16; ++mr){
    const int m = half * 16 + mr;
    const float rad = cosf((float)f * ((float)M_PI * 0.2f) * rbuf[m]) * cbuf[m];
    const unsigned short h = bf16rn(rad);
    rHi[m * T_STRIDE + f] = h;
    rLo[m * T_STRIDE + f] = bf16rn(rad - bfhi_to_f(h));
  }
  __syncthreads();

  const int lane = tid & 63, wave = tid >> 6, quad = lane >> 4, l16 = lane & 15;
  f32x4 acc[2][3][2];
  #pragma unroll
  for (int mt = 0; mt < 2; ++mt)
    #pragma unroll
    for (int l = 0; l < 3; ++l)
      #pragma unroll
      for (int n2 = 0; n2 < 2; ++n2)
        acc[mt][l][n2] = f32x4{0.f, 0.f, 0.f, 0.f};

  #pragma unroll
  for (int mt = 0; mt < 2; ++mt){
    #pragma unroll
    for (int ks = 0; ks < 4; ++ks){
      const bfrag ah = *(const bfrag*)&rHi[(mt * 16 + l16) * T_STRIDE + 32 * ks + 8 * quad];
      const bfrag al = *(const bfrag*)&rLo[(mt * 16 + l16) * T_STRIDE + 32 * ks + 8 * quad];
      #pragma unroll
      for (int l = 0; l < 3; ++l){
        #pragma unroll
        for (int n2 = 0; n2 < 2; ++n2){
          const int nt = 2 * wave + n2;
          const size_t off = ((size_t)((l * 8 + nt) * 4 + ks)) * 512 + lane * 8;
          const bfrag bh = *(const bfrag*)(W3hi + off);
          const bfrag bl = *(const bfrag*)(W3lo + off);
          acc[mt][l][n2] = __builtin_amdgcn_mfma_f32_16x16x32_bf16(ah, bh, acc[mt][l][n2], 0, 0, 0);
          acc[mt][l][n2] = __builtin_amdgcn_mfma_f32_16x16x32_bf16(al, bh, acc[mt][l][n2], 0, 0, 0);
          acc[mt][l][n2] = __builtin_amdgcn_mfma_f32_16x16x32_bf16(ah, bl, acc[mt][l][n2], 0, 0, 0);
        }
      }
    }
  }

  #pragma unroll
  for (int mt = 0; mt < 2; ++mt)
    #pragma unroll
    for (int l = 0; l < 3; ++l)
      #pragma unroll
      for (int n2 = 0; n2 < 2; ++n2){
        const int col = 16 * (2 * wave + n2) + l16;
        #pragma unroll
        for (int rr = 0; rr < 4; ++rr){
          const int e = e0 + mt * 16 + 4 * quad + rr;
          if (e < n_edges){
            float v = acc[mt][l][n2][rr];
            if (l == 0) v += b3[col];
            out[(size_t)e * (NM * NF) + l * NF + col] = v;
          }
        }
      }
}

// ================= TP accumulation (compile-time partitioned) =================
template<int CG>
__device__ __forceinline__ void tp_accum(const float* y2col /* = &y2_lds[g] */,
                                         const float bd[9], const float wp[NPATHS_C],
                                         float o[13]){
  constexpr int t0 = (CG == 0) ? 0 : TP_SPLIT;
  constexpr int t1 = (CG == 0) ? TP_SPLIT : TPN;
  constexpr int cbase = (CG == 0) ? 0 : 13;
  float y2b = 0.f;
  #pragma unroll
  for (int t = t0; t < t1; ++t){
    if (t == t0 || STP.e[t].b != STP.e[t-1].b)     // folds at compile time
      y2b = y2col[STP.e[t].b * Y_STRIDE];
    o[STP.e[t].c - cbase] = fmaf(STP.e[t].v * wp[STP.e[t].p],
                                 bd[STP.e[t].a] * y2b,
                                 o[STP.e[t].c - cbase]);
  }
}

// ================= kernel B: per-edge fused pipeline =================
__global__ __launch_bounds__(256, 5) void edge_kernel(const float* __restrict__ Z,
                                                      const int*   __restrict__ nbr,
                                                      const float* __restrict__ disp,
                                                      const float* __restrict__ b1,
                                                      const short* __restrict__ W2hi,
                                                      const short* __restrict__ W2lo,
                                                      const float* __restrict__ b2,
                                                      const float* __restrict__ wtp,
                                                      float* __restrict__ out){
  __shared__ unsigned short tHi[32 * T_STRIDE];   //  8704 B
  __shared__ unsigned short tLo[32 * T_STRIDE];   //  8704 B
  __shared__ float y2_lds[NM * Y_STRIDE];         // 12900 B
  __shared__ float nbuf[2 * NF];                  //  1024 B
  __shared__ float y0buf[NF];                     //   512 B  -> 31844 B total

  const int e   = blockIdx.x;
  const int tid = threadIdx.x;
  const int f   = tid & 127, half = tid >> 7;
  const int i = nbr[2 * e], j = nbr[2 * e + 1];
  const float* Zi = Z + (size_t)i * NM * NF;
  const float* Zj = Z + (size_t)j * NM * NF;

  const float dx = disp[3 * e], dy = disp[3 * e + 1], dz = disp[3 * e + 2];
  const float r  = sqrtf(dx * dx + dy * dy + dz * dz + 1e-12f);

  // ---- P1a: gather + partial norm, carry v in registers (single Z pass) ----
  float vreg[13];
  float n2 = 0.f;
  if (!half){
    #pragma unroll
    for (int k = 0; k < 13; ++k){
      float v = Zi[k * NF + f] + Zj[k * NF + f];
      if (k == 0) v += b1[f];
      vreg[k] = v;
      n2 = fmaf(v, v, n2);
    }
    y0buf[f] = vreg[0];
  } else {
    #pragma unroll
    for (int k = 0; k < 12; ++k){
      const float v = Zi[(13 + k) * NF + f] + Zj[(13 + k) * NF + f];
      vreg[k] = v;
      n2 = fmaf(v, v, n2);
    }
  }
  nbuf[half * NF + f] = n2;
  __syncthreads();

  // ---- P1b: normalize + gated mish -> t (bf16 hi/lo) in LDS ----
  const float inv = 1.0f / sqrtf(nbuf[f] + nbuf[NF + f] + 1e-6f);
  const float s   = y0buf[f] * inv;
  const float sp  = fmaxf(s, 0.f) + log1pf(expf(-fabsf(s)));
  const float th  = tanhf(sp);
  const float sg  = 1.0f / (1.0f + expf(-s));
  const float dm  = th + s * (1.f - th * th) * sg;
  if (!half){
    #pragma unroll
    for (int k = 0; k < 13; ++k){
      const float tv = (k == 0) ? (s * th) : (vreg[k] * inv * dm);
      const unsigned short h = bf16rn(tv);
      tHi[k * T_STRIDE + f] = h;
      tLo[k * T_STRIDE + f] = bf16rn(tv - bfhi_to_f(h));
    }
  } else {
    #pragma unroll
    for (int k = 0; k < 12; ++k){
      const float tv = vreg[k] * inv * dm;
      const unsigned short h = bf16rn(tv);
      tHi[(13 + k) * T_STRIDE + f] = h;
      tLo[(13 + k) * T_STRIDE + f] = bf16rn(tv - bfhi_to_f(h));
    }
    #pragma unroll
    for (int m = 25; m < 32; ++m){ tHi[m * T_STRIDE + f] = 0; tLo[m * T_STRIDE + f] = 0; }
  }
  __syncthreads();

  // ---- P2: W2 GEMM (split-bf16 MFMA) with fused residual(+b2) epilogue ----
  const int lane = tid & 63, wave = tid >> 6;
  f32x4 acc[5][2];
  #pragma unroll
  for (int l = 0; l < 5; ++l)
    #pragma unroll
    for (int c = 0; c < 2; ++c)
      acc[l][c] = f32x4{0.f, 0.f, 0.f, 0.f};

  mfma_gemm(tHi, tLo, W2hi, W2lo, lane, wave, acc);

  const int quad = lane >> 4, l16 = lane & 15;
  #pragma unroll
  for (int l = 0; l < 5; ++l)
    #pragma unroll
    for (int c = 0; c < 2; ++c){
      const int col = 16 * (2 * wave + c) + l16;
      #pragma unroll
      for (int rr = 0; rr < 4; ++rr){
        if (rr <= 2 * l){
          const int row = 4 * quad + rr;
          if (row <= 2 * l){
            const int m = l * l + row;
            float v = acc[l][c][rr]
                    + bfhi_to_f(tHi[m * T_STRIDE + col])
                    + bfhi_to_f(tLo[m * T_STRIDE + col]);
            if (l == 0) v += b2[col];      // m==0 row only (row<=0 enforced)
            y2_lds[m * Y_STRIDE + col] = v;
          }
        }
      }
    }
  __syncthreads();

  // ---- P4: tensor product + store ----
  const float rinv = 1.0f / r;
  const float ux = dx * rinv, uy = dy * rinv, uz = dz * rinv;
  const float s3 = 1.7320508075688772f;
  const size_t ebase = (size_t)e * (NM * NF);
  float bd[9];
  {
    // rw parked in out rows 0..2 by radial_kernel (b3 already folded into rw0)
    const float rw0 = out[ebase + f];
    const float rw1 = out[ebase + NF + f];
    const float rw2 = out[ebase + 2 * NF + f];
    bd[0] = rw0;
    bd[1] = uy * rw1;
    bd[2] = uz * rw1;
    bd[3] = ux * rw1;
    bd[4] = (s3 * ux * uy) * rw2;
    bd[5] = (s3 * uy * uz) * rw2;
    bd[6] = (0.5f * (3.f * uz * uz - 1.f)) * rw2;
    bd[7] = (s3 * ux * uz) * rw2;
    bd[8] = (0.5f * s3 * (ux * ux - uy * uy)) * rw2;
  }
  float wp[NPATHS_C];
  #pragma unroll
  for (int p = 0; p < NPATHS_C; ++p) wp[p] = wtp[p * NF + f];

  float o[13];
  #pragma unroll
  for (int k = 0; k < 13; ++k) o[k] = 0.f;

  float* ob = out + ebase;
  if (!half){
    tp_accum<0>(&y2_lds[f], bd, wp, o);
    #pragma unroll
    for (int k = 0; k < 13; ++k) ob[k * NF + f] = o[k];
  } else {
    tp_accum<1>(&y2_lds[f], bd, wp, o);
    #pragma unroll
    for (int k = 0; k < 12; ++k) ob[(13 + k) * NF + f] = o[k];
  }
}

} // anonymous namespace

extern "C" void kernel_launch(void* const* d_in, const int* in_sizes, int n_in,
                              void* d_out, int out_size, void* d_ws, size_t ws_size,
                              hipStream_t stream) {
  (void)n_in; (void)out_size;
  const float* A    = (const float*)d_in[0];
  const int*   nbr  = (const int*)  d_in[1];
  const float* disp = (const float*)d_in[2];
  const float* W1   = (const float*)d_in[3];
  const float* b1   = (const float*)d_in[4];
  const float* W2   = (const float*)d_in[5];
  const float* b2   = (const float*)d_in[6];
  const float* W3   = (const float*)d_in[7];
  const float* b3   = (const float*)d_in[8];
  const float* wtp  = (const float*)d_in[9];
  float* out = (float*)d_out;

  const int n_atoms = in_sizes[0] / (NM * NF);
  const int n_edges = in_sizes[1] / 2;

  // ws layout: 4 swizzled W1/W2 arrays (163840 B each) + 2 swizzled W3 arrays
  // (98304 B each) + Z (n_atoms*25*128 fp32)
  const size_t wsz   = (size_t)5 * 8 * 4 * 64 * 8 * sizeof(short);  // 163840 B
  const size_t wsz3  = (size_t)3 * 8 * 4 * 64 * 8 * sizeof(short);  //  98304 B
  const size_t w3off = 4 * wsz;
  const size_t zoff  = w3off + 2 * wsz3;
  const size_t need  = zoff + (size_t)n_atoms * NM * NF * sizeof(float);
  if (ws_size < need) return;

  short* W1hi = (short*)((char*)d_ws + 0 * wsz);
  short* W1lo = (short*)((char*)d_ws + 1 * wsz);
  short* W2hi = (short*)((char*)d_ws + 2 * wsz);
  short* W2lo = (short*)((char*)d_ws + 3 * wsz);
  short* W3hi = (short*)((char*)d_ws + w3off);
  short* W3lo = (short*)((char*)d_ws + w3off + wsz3);
  float* Z    = (float*)((char*)d_ws + zoff);

  prep_kernel<<<dim3(104), dim3(256), 0, stream>>>(W1, W2, W3, W1hi, W1lo,
                                                   W2hi, W2lo, W3hi, W3lo);
  atoms_kernel<<<dim3(n_atoms), dim3(256), 0, stream>>>(A, W1hi, W1lo, Z);
  radial_kernel<<<dim3((n_edges + 31) / 32), dim3(256), 0, stream>>>(disp, W3hi, W3lo,
                                                                     b3, out, n_edges);
  edge_kernel<<<dim3(n_edges), dim3(256), 0, stream>>>(Z, nbr, disp, b1, W2hi, W2lo,
                                                       b2, wtp, out);
}

// Round 3
// 539.940 us; speedup vs baseline: 1.3887x; 1.0846x over previous
//
#include <hip/hip_runtime.h>
#include <math.h>

#ifndef M_PI
#define M_PI 3.14159265358979323846
#endif

namespace {

constexpr int NF = 128;   // feature width
constexpr int NM = 25;    // total m components (l=0..4)

// ================= compile-time real Clebsch-Gordan tables =================
struct CD { double re, im; };
constexpr CD cmulc(CD x, CD y){ return CD{x.re*y.re - x.im*y.im, x.re*y.im + x.im*y.re}; }

constexpr double cfact(int n){ double r = 1.0; for (int i = 2; i <= n; ++i) r *= (double)i; return r; }

constexpr double csqrt_(double x){
  if (x <= 0.0) return 0.0;
  double g = x < 1.0 ? 1.0 : x;
  for (int i = 0; i < 48; ++i) g = 0.5 * (g + x / g);
  return g;
}

constexpr double cgc_(int l1, int l2, int l3, int m1, int m2, int m3){
  if (m1 + m2 != m3) return 0.0;
  int dmin = l1 > l2 ? l1 - l2 : l2 - l1;
  if (l3 < dmin || l3 > l1 + l2) return 0.0;
  double pre = csqrt_((2.0*l3 + 1.0) * cfact(l3 + l1 - l2) * cfact(l3 - l1 + l2) *
                      cfact(l1 + l2 - l3) / cfact(l1 + l2 + l3 + 1));
  pre *= csqrt_(cfact(l3 + m3) * cfact(l3 - m3) * cfact(l1 - m1) * cfact(l1 + m1) *
                cfact(l2 - m2) * cfact(l2 + m2));
  double s = 0.0;
  for (int k = 0; k <= l1 + l2 - l3; ++k){
    int a0 = k, a1 = l1 + l2 - l3 - k, a2 = l1 - m1 - k;
    int a3 = l2 + m2 - k, a4 = l3 - l2 + m1 + k, a5 = l3 - l1 - m2 + k;
    if (a0 < 0 || a1 < 0 || a2 < 0 || a3 < 0 || a4 < 0 || a5 < 0) continue;
    double d = cfact(a0)*cfact(a1)*cfact(a2)*cfact(a3)*cfact(a4)*cfact(a5);
    s += ((k & 1) ? -1.0 : 1.0) / d;
  }
  return pre * s;
}

constexpr CD umat(int l, int a, int A){
  const double is2 = 0.70710678118654752440;
  int ma = a - l, mA = A - l;
  if (ma == 0) return (mA == 0) ? CD{1.0, 0.0} : CD{0.0, 0.0};
  if (ma > 0){
    double sg = (ma & 1) ? -1.0 : 1.0;
    if (mA ==  ma) return CD{sg * is2, 0.0};
    if (mA == -ma) return CD{0.0, sg * is2};
    return CD{0.0, 0.0};
  }
  if (mA == -ma) return CD{is2, 0.0};
  if (mA ==  ma) return CD{0.0, -is2};
  return CD{0.0, 0.0};
}

struct TpEntry { int a, b, c, p; float v; };
struct TpTable { TpEntry e[1024]; int n; int npaths; };

constexpr TpTable build_tp(){
  TpTable T{};
  T.n = 0;
  int p = 0;
  for (int l1 = 0; l1 < 3; ++l1)
  for (int l2 = 0; l2 < 5; ++l2)
  for (int l3 = 0; l3 < 5; ++l3){
    int dmin = l1 > l2 ? l1 - l2 : l2 - l1;
    if (l3 < dmin || l3 > l1 + l2) continue;
    if ((l1 + l2 + l3) & 1) continue;
    double Cr[5][9][9] = {};
    for (int a = 0; a <= 2*l1; ++a)
    for (int b = 0; b <= 2*l2; ++b){
      int m1 = a - l1, m2 = b - l2, m3 = m1 + m2;
      if (m3 < -l3 || m3 > l3) continue;
      double cg = cgc_(l1, l2, l3, m1, m2, m3);
      if (cg == 0.0) continue;
      int c3 = l3 + m3;
      int Al[2] = { l1 + m1, l1 - m1 }; int nA = (m1 == 0) ? 1 : 2;
      int Bl[2] = { l2 + m2, l2 - m2 }; int nB = (m2 == 0) ? 1 : 2;
      int Cl[2] = { l3 + m3, l3 - m3 }; int nC = (m3 == 0) ? 1 : 2;
      for (int ia = 0; ia < nA; ++ia)
      for (int ib = 0; ib < nB; ++ib)
      for (int ic = 0; ic < nC; ++ic){
        CD u1 = umat(l1, a, Al[ia]);
        CD u2 = umat(l2, b, Bl[ib]);
        CD u3 = umat(l3, c3, Cl[ic]);
        CD t12 = cmulc(u1, u2);
        double re = t12.re * u3.re + t12.im * u3.im;   // Re(t12 * conj(u3))
        Cr[Al[ia]][Bl[ib]][Cl[ic]] += cg * re;
      }
    }
    for (int A = 0; A <= 2*l1; ++A)
    for (int B = 0; B <= 2*l2; ++B)
    for (int Cc = 0; Cc <= 2*l3; ++Cc){
      double v = Cr[A][B][Cc];
      if (v > 1e-12 || v < -1e-12){
        T.e[T.n].a = l1*l1 + A;
        T.e[T.n].b = l2*l2 + B;
        T.e[T.n].c = l3*l3 + Cc;
        T.e[T.n].p = p;
        T.e[T.n].v = (float)v;
        ++T.n;
      }
    }
    ++p;
  }
  T.npaths = p;
  return T;
}

constexpr TpTable TPT = build_tp();
constexpr int TPN      = TPT.n;
constexpr int NPATHS_C = TPT.npaths;
static_assert(NPATHS_C == 23, "path count mismatch vs reference PATHS");
static_assert(TPN <= 1024, "TP table overflow");

// Sorted copy: grouped by (c<13 ? 0 : 1) major, then by b ascending.
struct TpSorted { TpEntry e[1024]; int n; int split; };
constexpr TpSorted sort_tp(){
  TpSorted S{}; S.n = TPT.n; S.split = 0;
  int k = 0;
  for (int half = 0; half < 2; ++half){
    for (int b = 0; b < NM; ++b)
      for (int t = 0; t < TPT.n; ++t){
        int h = (TPT.e[t].c >= 13) ? 1 : 0;
        if (h == half && TPT.e[t].b == b) S.e[k++] = TPT.e[t];
      }
    if (half == 0) S.split = k;
  }
  return S;
}
constexpr TpSorted STP = sort_tp();
static_assert(STP.n == TPN, "sort lost entries");
constexpr int TP_SPLIT = STP.split;

// ================= MFMA helpers =================
using bfrag = __attribute__((ext_vector_type(8))) short;   // 8 bf16
using f32x4 = __attribute__((ext_vector_type(4))) float;

__device__ __forceinline__ unsigned short bf16rn(float x){
  unsigned u = __float_as_uint(x);
  unsigned r = (u + 0x7FFFu + ((u >> 16) & 1u)) >> 16;
  return (unsigned short)r;
}
__device__ __forceinline__ float bfhi_to_f(unsigned short h){
  return __uint_as_float((unsigned)h << 16);
}

constexpr int T_STRIDE = 136;  // bf16 elements per padded t-row
constexpr int Y_STRIDE = 129;  // fp32 elements per padded y2 row

// ================= prep kernel: swizzle W1/W2/W3 into B-fragment order, bf16 hi/lo ====
// B-frag for mfma_f32_16x16x32_bf16: lane L holds B[k = 8*(L>>4)+j][n = L&15], j=0..7.
// Frag id = (l*8 + nt)*4 + ks ; element offset = frag*512 + L*8 + j (shorts).
__global__ __launch_bounds__(256) void prep_kernel(const float* __restrict__ W1,
                                                   const float* __restrict__ W2,
                                                   const float* __restrict__ W3,
                                                   short* __restrict__ W1hi, short* __restrict__ W1lo,
                                                   short* __restrict__ W2hi, short* __restrict__ W2lo,
                                                   short* __restrict__ W3hi, short* __restrict__ W3lo){
  const int t = blockIdx.x * 256 + threadIdx.x;      // 0 .. 26623
  if (t >= 26624) return;
  int arr, s;
  if (t < 10240)      { arr = 0; s = t; }
  else if (t < 20480) { arr = 1; s = t - 10240; }
  else                { arr = 2; s = t - 20480; }
  const int lane = s & 63;
  const int ks   = (s >> 6) & 3;
  const int nt   = (s >> 8) & 7;
  const int l    = s >> 11;                          // 0..4 (0..2 for W3)
  const float* W = (arr == 0) ? W1 : (arr == 1) ? W2 : W3;
  short* Hi = (arr == 0) ? W1hi : (arr == 1) ? W2hi : W3hi;
  short* Lo = (arr == 0) ? W1lo : (arr == 1) ? W2lo : W3lo;
  const int g = 16 * nt + (lane & 15);
  short hi8[8], lo8[8];
  #pragma unroll
  for (int j = 0; j < 8; ++j){
    const int f = 32 * ks + 8 * (lane >> 4) + j;
    const float w = W[(l * NF + f) * NF + g];
    unsigned short h = bf16rn(w);
    hi8[j] = (short)h;
    lo8[j] = (short)bf16rn(w - bfhi_to_f(h));
  }
  const size_t off = (size_t)s * 8;
  *(bfrag*)(Hi + off) = *(bfrag*)hi8;
  *(bfrag*)(Lo + off) = *(bfrag*)lo8;
}

// ================= dual-tile GEMM body (B loaded once, reused for 2 A-tiles) =========
// 512 threads: wave w (0..7) owns output cols 16w..16w+15 for BOTH tiles.
__device__ __forceinline__ void mfma_gemm2(const unsigned short* tHi0, const unsigned short* tLo0,
                                           const unsigned short* tHi1, const unsigned short* tLo1,
                                           const short* __restrict__ Whi, const short* __restrict__ Wlo,
                                           int lane, int wave, f32x4 acc[5][2]){
  const int quad = lane >> 4, l16 = lane & 15;
  #pragma unroll
  for (int l = 0; l < 5; ++l){
    const int mb = l * l;
    #pragma unroll
    for (int ks = 0; ks < 4; ++ks){
      const size_t off = ((size_t)((l * 8 + wave) * 4 + ks)) * 512 + lane * 8;
      const bfrag bh = *(const bfrag*)(Whi + off);
      const bfrag bl = *(const bfrag*)(Wlo + off);
      const int aoff = (mb + l16) * T_STRIDE + 32 * ks + 8 * quad;
      {
        const bfrag ah = *(const bfrag*)&tHi0[aoff];
        const bfrag al = *(const bfrag*)&tLo0[aoff];
        acc[l][0] = __builtin_amdgcn_mfma_f32_16x16x32_bf16(ah, bh, acc[l][0], 0, 0, 0);
        acc[l][0] = __builtin_amdgcn_mfma_f32_16x16x32_bf16(al, bh, acc[l][0], 0, 0, 0);
        acc[l][0] = __builtin_amdgcn_mfma_f32_16x16x32_bf16(ah, bl, acc[l][0], 0, 0, 0);
      }
      {
        const bfrag ah = *(const bfrag*)&tHi1[aoff];
        const bfrag al = *(const bfrag*)&tLo1[aoff];
        acc[l][1] = __builtin_amdgcn_mfma_f32_16x16x32_bf16(ah, bh, acc[l][1], 0, 0, 0);
        acc[l][1] = __builtin_amdgcn_mfma_f32_16x16x32_bf16(al, bh, acc[l][1], 0, 0, 0);
        acc[l][1] = __builtin_amdgcn_mfma_f32_16x16x32_bf16(ah, bl, acc[l][1], 0, 0, 0);
      }
    }
  }
}

// ================= mid kernel: 2 atoms/block GEMM  OR  64-edge radial GEMM ==========
// Fused into one dispatch so the small radial grid overlaps the atoms grid.
__global__ __launch_bounds__(512, 4) void mid_kernel(const float* __restrict__ A,
                                                     const short* __restrict__ W1hi,
                                                     const short* __restrict__ W1lo,
                                                     float* __restrict__ Z,
                                                     const float* __restrict__ disp,
                                                     const short* __restrict__ W3hi,
                                                     const short* __restrict__ W3lo,
                                                     const float* __restrict__ b3,
                                                     float* __restrict__ out,
                                                     int n_atoms, int n_edges, int nA2){
  __shared__ unsigned short sHi[2][32 * T_STRIDE];   // 17408 B
  __shared__ unsigned short sLo[2][32 * T_STRIDE];   // 17408 B
  __shared__ float rbuf[64];
  __shared__ float cbuf[64];

  const int tid  = threadIdx.x;
  const int f    = tid & 127;
  const int q    = tid >> 7;          // quarter 0..3
  const int lane = tid & 63, wave = tid >> 6;
  const int quad = lane >> 4, l16 = lane & 15;

  if ((int)blockIdx.x < nA2){
    // ---------------- 2-atom W1 GEMM ----------------
    const int as   = q >> 1;          // atom select
    const int half = q & 1;
    int a = 2 * blockIdx.x + as;
    if (a >= n_atoms) a = n_atoms - 1;          // duplicate-last clamp (benign)
    const float* Ab = A + (size_t)a * NM * NF;
    unsigned short* hi = sHi[as];
    unsigned short* lo = sLo[as];
    const int m0 = half ? 13 : 0, m1 = half ? 25 : 13;
    for (int m = m0; m < m1; ++m){
      const float x = Ab[m * NF + f];
      const unsigned short h = bf16rn(x);
      hi[m * T_STRIDE + f] = h;
      lo[m * T_STRIDE + f] = bf16rn(x - bfhi_to_f(h));
    }
    if (half){
      for (int m = 25; m < 32; ++m){ hi[m * T_STRIDE + f] = 0; lo[m * T_STRIDE + f] = 0; }
    }
    __syncthreads();

    f32x4 acc[5][2];
    #pragma unroll
    for (int l = 0; l < 5; ++l){ acc[l][0] = f32x4{0,0,0,0}; acc[l][1] = f32x4{0,0,0,0}; }
    mfma_gemm2(sHi[0], sLo[0], sHi[1], sLo[1], W1hi, W1lo, lane, wave, acc);

    #pragma unroll
    for (int as2 = 0; as2 < 2; ++as2){
      int aa = 2 * blockIdx.x + as2;
      if (aa >= n_atoms) aa = n_atoms - 1;
      float* Zb = Z + (size_t)aa * NM * NF;
      const int col = 16 * wave + l16;
      #pragma unroll
      for (int l = 0; l < 5; ++l)
        #pragma unroll
        for (int r = 0; r < 4; ++r){
          if (r <= 2 * l){
            const int row = 4 * quad + r;
            if (row <= 2 * l)
              Zb[(l * l + row) * NF + col] = acc[l][as2][r];
          }
        }
    }
  } else {
    // ---------------- 64-edge radial GEMM: rw = rad @ W3 (+b3 on l=0) ----------------
    const int e0 = (blockIdx.x - nA2) * 64;
    if (tid < 64){
      const int e = e0 + tid;
      float r = 1.f, cut = 0.f;
      if (e < n_edges){
        const float dx = disp[3 * e], dy = disp[3 * e + 1], dz = disp[3 * e + 2];
        r = sqrtf(dx * dx + dy * dy + dz * dz + 1e-12f);
        const float uc  = r * 0.2f;
        const float den = fmaxf(1.f - uc * uc, 1e-9f);
        cut = (uc < 1.f) ? expf(1.f - 1.f / den) : 0.f;
      }
      rbuf[tid] = r; cbuf[tid] = cut;
    }
    __syncthreads();

    unsigned short* hi = &sHi[0][0];   // flat 64 x T_STRIDE
    unsigned short* lo = &sLo[0][0];
    #pragma unroll
    for (int mr = 0; mr < 16; ++mr){
      const int m = q * 16 + mr;
      const float rad = cosf((float)f * ((float)M_PI * 0.2f) * rbuf[m]) * cbuf[m];
      const unsigned short h = bf16rn(rad);
      hi[m * T_STRIDE + f] = h;
      lo[m * T_STRIDE + f] = bf16rn(rad - bfhi_to_f(h));
    }
    __syncthreads();

    f32x4 acc[4][3];
    #pragma unroll
    for (int mt = 0; mt < 4; ++mt)
      #pragma unroll
      for (int l = 0; l < 3; ++l) acc[mt][l] = f32x4{0,0,0,0};

    #pragma unroll
    for (int l = 0; l < 3; ++l){
      #pragma unroll
      for (int ks = 0; ks < 4; ++ks){
        const size_t off = ((size_t)((l * 8 + wave) * 4 + ks)) * 512 + lane * 8;
        const bfrag bh = *(const bfrag*)(W3hi + off);
        const bfrag bl = *(const bfrag*)(W3lo + off);
        #pragma unroll
        for (int mt = 0; mt < 4; ++mt){
          const int aoff = (mt * 16 + l16) * T_STRIDE + 32 * ks + 8 * quad;
          const bfrag ah = *(const bfrag*)&hi[aoff];
          const bfrag al = *(const bfrag*)&lo[aoff];
          acc[mt][l] = __builtin_amdgcn_mfma_f32_16x16x32_bf16(ah, bh, acc[mt][l], 0, 0, 0);
          acc[mt][l] = __builtin_amdgcn_mfma_f32_16x16x32_bf16(al, bh, acc[mt][l], 0, 0, 0);
          acc[mt][l] = __builtin_amdgcn_mfma_f32_16x16x32_bf16(ah, bl, acc[mt][l], 0, 0, 0);
        }
      }
    }

    const int col = 16 * wave + l16;
    #pragma unroll
    for (int mt = 0; mt < 4; ++mt)
      #pragma unroll
      for (int l = 0; l < 3; ++l)
        #pragma unroll
        for (int rr = 0; rr < 4; ++rr){
          const int e = e0 + mt * 16 + 4 * quad + rr;
          if (e < n_edges){
            float v = acc[mt][l][rr];
            if (l == 0) v += b3[col];
            out[(size_t)e * (NM * NF) + l * NF + col] = v;
          }
        }
  }
}

// ================= TP accumulation (compile-time partitioned) =================
template<int CG>
__device__ __forceinline__ void tp_accum(const float* y2col,
                                         const float bd[9], const float wp[NPATHS_C],
                                         float o[13]){
  constexpr int t0 = (CG == 0) ? 0 : TP_SPLIT;
  constexpr int t1 = (CG == 0) ? TP_SPLIT : TPN;
  constexpr int cbase = (CG == 0) ? 0 : 13;
  float y2b = 0.f;
  #pragma unroll
  for (int t = t0; t < t1; ++t){
    if (t == t0 || STP.e[t].b != STP.e[t-1].b)     // folds at compile time
      y2b = y2col[STP.e[t].b * Y_STRIDE];
    o[STP.e[t].c - cbase] = fmaf(STP.e[t].v * wp[STP.e[t].p],
                                 bd[STP.e[t].a] * y2b,
                                 o[STP.e[t].c - cbase]);
  }
}

// ================= edge kernel: 2 edges per 512-thread block =================
__global__ __launch_bounds__(512, 4) void edge_kernel(const float* __restrict__ Z,
                                                      const int*   __restrict__ nbr,
                                                      const float* __restrict__ disp,
                                                      const float* __restrict__ b1,
                                                      const short* __restrict__ W2hi,
                                                      const short* __restrict__ W2lo,
                                                      const float* __restrict__ b2,
                                                      const float* __restrict__ wtp,
                                                      float* __restrict__ out,
                                                      int n_edges){
  __shared__ unsigned short tHi[2][32 * T_STRIDE];  // 17408 B
  __shared__ unsigned short tLo[2][32 * T_STRIDE];  // 17408 B
  __shared__ float y2_lds[2][NM * Y_STRIDE];        // 25800 B
  __shared__ float nbuf[4 * NF];                    //  2048 B
  __shared__ float y0buf[2][NF];                    //  1024 B   -> 63688 B

  const int tid  = threadIdx.x;
  const int f    = tid & 127;
  const int q    = tid >> 7;          // quarter 0..3
  const int es   = q >> 1;            // edge select 0/1
  const int half = q & 1;

  int e = 2 * blockIdx.x + es;
  if (e >= n_edges) e = n_edges - 1;  // duplicate-last clamp (benign)
  const int i = nbr[2 * e], j = nbr[2 * e + 1];
  const float* Zi = Z + (size_t)i * NM * NF;
  const float* Zj = Z + (size_t)j * NM * NF;

  const float dx = disp[3 * e], dy = disp[3 * e + 1], dz = disp[3 * e + 2];
  const float r  = sqrtf(dx * dx + dy * dy + dz * dz + 1e-12f);

  // ---- P1a: gather + partial norm, carry v in registers (single Z pass) ----
  float vreg[13];
  float n2 = 0.f;
  if (!half){
    #pragma unroll
    for (int k = 0; k < 13; ++k){
      float v = Zi[k * NF + f] + Zj[k * NF + f];
      if (k == 0) v += b1[f];
      vreg[k] = v;
      n2 = fmaf(v, v, n2);
    }
    y0buf[es][f] = vreg[0];
  } else {
    #pragma unroll
    for (int k = 0; k < 12; ++k){
      const float v = Zi[(13 + k) * NF + f] + Zj[(13 + k) * NF + f];
      vreg[k] = v;
      n2 = fmaf(v, v, n2);
    }
  }
  nbuf[(es * 2 + half) * NF + f] = n2;
  __syncthreads();

  // ---- P1b: normalize + gated mish -> t (bf16 hi/lo) in LDS ----
  const float inv = 1.0f / sqrtf(nbuf[(es * 2) * NF + f] + nbuf[(es * 2 + 1) * NF + f] + 1e-6f);
  const float s   = y0buf[es][f] * inv;
  const float sp  = fmaxf(s, 0.f) + log1pf(expf(-fabsf(s)));
  const float th  = tanhf(sp);
  const float sg  = 1.0f / (1.0f + expf(-s));
  const float dm  = th + s * (1.f - th * th) * sg;
  unsigned short* hi = tHi[es];
  unsigned short* lo = tLo[es];
  if (!half){
    #pragma unroll
    for (int k = 0; k < 13; ++k){
      const float tv = (k == 0) ? (s * th) : (vreg[k] * inv * dm);
      const unsigned short h = bf16rn(tv);
      hi[k * T_STRIDE + f] = h;
      lo[k * T_STRIDE + f] = bf16rn(tv - bfhi_to_f(h));
    }
  } else {
    #pragma unroll
    for (int k = 0; k < 12; ++k){
      const float tv = vreg[k] * inv * dm;
      const unsigned short h = bf16rn(tv);
      hi[(13 + k) * T_STRIDE + f] = h;
      lo[(13 + k) * T_STRIDE + f] = bf16rn(tv - bfhi_to_f(h));
    }
    #pragma unroll
    for (int m = 25; m < 32; ++m){ hi[m * T_STRIDE + f] = 0; lo[m * T_STRIDE + f] = 0; }
  }
  __syncthreads();

  // ---- P2: W2 GEMM (split-bf16 MFMA, B reused across both edges) ----
  const int lane = tid & 63, wave = tid >> 6;
  f32x4 acc[5][2];
  #pragma unroll
  for (int l = 0; l < 5; ++l){ acc[l][0] = f32x4{0,0,0,0}; acc[l][1] = f32x4{0,0,0,0}; }

  mfma_gemm2(tHi[0], tLo[0], tHi[1], tLo[1], W2hi, W2lo, lane, wave, acc);

  const int quad = lane >> 4, l16 = lane & 15;
  const int col = 16 * wave + l16;
  #pragma unroll
  for (int es2 = 0; es2 < 2; ++es2){
    #pragma unroll
    for (int l = 0; l < 5; ++l)
      #pragma unroll
      for (int rr = 0; rr < 4; ++rr){
        if (rr <= 2 * l){
          const int row = 4 * quad + rr;
          if (row <= 2 * l){
            const int m = l * l + row;
            float v = acc[l][es2][rr]
                    + bfhi_to_f(tHi[es2][m * T_STRIDE + col])
                    + bfhi_to_f(tLo[es2][m * T_STRIDE + col]);
            if (l == 0) v += b2[col];
            y2_lds[es2][m * Y_STRIDE + col] = v;
          }
        }
      }
  }
  __syncthreads();

  // ---- P4a: read parked rw + weights into registers BEFORE the store fence ----
  const float rinv = 1.0f / r;
  const float ux = dx * rinv, uy = dy * rinv, uz = dz * rinv;
  const float s3 = 1.7320508075688772f;
  const size_t ebase = (size_t)e * (NM * NF);
  float bd[9];
  {
    const float rw0 = out[ebase + f];
    const float rw1 = out[ebase + NF + f];
    const float rw2 = out[ebase + 2 * NF + f];
    bd[0] = rw0;
    bd[1] = uy * rw1;
    bd[2] = uz * rw1;
    bd[3] = ux * rw1;
    bd[4] = (s3 * ux * uy) * rw2;
    bd[5] = (s3 * uy * uz) * rw2;
    bd[6] = (0.5f * (3.f * uz * uz - 1.f)) * rw2;
    bd[7] = (s3 * ux * uz) * rw2;
    bd[8] = (0.5f * s3 * (ux * ux - uy * uy)) * rw2;
  }
  float wp[NPATHS_C];
  #pragma unroll
  for (int p = 0; p < NPATHS_C; ++p) wp[p] = wtp[p * NF + f];
  __syncthreads();   // fence: all rw reads complete before any thread stores to out

  // ---- P4b: tensor product + store ----
  float o[13];
  #pragma unroll
  for (int k = 0; k < 13; ++k) o[k] = 0.f;

  float* ob = out + ebase;
  if (!half){
    tp_accum<0>(&y2_lds[es][f], bd, wp, o);
    #pragma unroll
    for (int k = 0; k < 13; ++k) ob[k * NF + f] = o[k];
  } else {
    tp_accum<1>(&y2_lds[es][f], bd, wp, o);
    #pragma unroll
    for (int k = 0; k < 12; ++k) ob[(13 + k) * NF + f] = o[k];
  }
}

} // anonymous namespace

extern "C" void kernel_launch(void* const* d_in, const int* in_sizes, int n_in,
                              void* d_out, int out_size, void* d_ws, size_t ws_size,
                              hipStream_t stream) {
  (void)n_in; (void)out_size;
  const float* A    = (const float*)d_in[0];
  const int*   nbr  = (const int*)  d_in[1];
  const float* disp = (const float*)d_in[2];
  const float* W1   = (const float*)d_in[3];
  const float* b1   = (const float*)d_in[4];
  const float* W2   = (const float*)d_in[5];
  const float* b2   = (const float*)d_in[6];
  const float* W3   = (const float*)d_in[7];
  const float* b3   = (const float*)d_in[8];
  const float* wtp  = (const float*)d_in[9];
  float* out = (float*)d_out;

  const int n_atoms = in_sizes[0] / (NM * NF);
  const int n_edges = in_sizes[1] / 2;

  // ws layout: 4 swizzled W1/W2 arrays (163840 B each) + 2 swizzled W3 arrays
  // (98304 B each) + Z (n_atoms*25*128 fp32)
  const size_t wsz   = (size_t)5 * 8 * 4 * 64 * 8 * sizeof(short);  // 163840 B
  const size_t wsz3  = (size_t)3 * 8 * 4 * 64 * 8 * sizeof(short);  //  98304 B
  const size_t w3off = 4 * wsz;
  const size_t zoff  = w3off + 2 * wsz3;
  const size_t need  = zoff + (size_t)n_atoms * NM * NF * sizeof(float);
  if (ws_size < need) return;

  short* W1hi = (short*)((char*)d_ws + 0 * wsz);
  short* W1lo = (short*)((char*)d_ws + 1 * wsz);
  short* W2hi = (short*)((char*)d_ws + 2 * wsz);
  short* W2lo = (short*)((char*)d_ws + 3 * wsz);
  short* W3hi = (short*)((char*)d_ws + w3off);
  short* W3lo = (short*)((char*)d_ws + w3off + wsz3);
  float* Z    = (float*)((char*)d_ws + zoff);

  const int nA2 = (n_atoms + 1) / 2;
  const int nR  = (n_edges + 63) / 64;

  prep_kernel<<<dim3(104), dim3(256), 0, stream>>>(W1, W2, W3, W1hi, W1lo,
                                                   W2hi, W2lo, W3hi, W3lo);
  mid_kernel<<<dim3(nA2 + nR), dim3(512), 0, stream>>>(A, W1hi, W1lo, Z, disp,
                                                       W3hi, W3lo, b3, out,
                                                       n_atoms, n_edges, nA2);
  edge_kernel<<<dim3((n_edges + 1) / 2), dim3(512), 0, stream>>>(Z, nbr, disp, b1,
                                                                 W2hi, W2lo, b2, wtp,
                                                                 out, n_edges);
}